// Round 1
// baseline (537.212 us; speedup 1.0000x reference)
//
#include <hip/hip_runtime.h>
#include <math.h>

// Problem constants (reference: N=5, B=8, C=256, H=W=32)
#define NN 5
#define CC 256
#define SSP 1024          // H*W
#define BB 8
#define TILE 32           // o-tile and s-tile
#define KC 32             // K chunk
#define XPAD 36           // x_s row pad (16B-aligned rows, conflict-free reads)
#define THRESHV 0.3f

// Fused kernel: per block computes a 32(o) x 32(s) tile for one b, for ALL i,j:
//   Y[i][j] = A_i @ X_j   (A_i = W1_i + W2_i), U[i] = W2_i @ X_i  (+bias later)
// then edge/threshold/softmax epilogue and writes 5 output planes.
__global__ __launch_bounds__(256, 2)
void fub_fused(const float* __restrict__ x,      // [5,8,256,1024]
               const float* __restrict__ w,      // [5,256,512]
               const float* __restrict__ bias,   // [5,256]
               float* __restrict__ out)          // [5,8,256,1024]
{
    __shared__ float a_s [NN][KC][TILE];   // A[i][k][o]   (stride 32: 2-way write alias = free)
    __shared__ float w2_s[NN][KC][TILE];   // W2[i][k][o]
    __shared__ float x_s [NN][KC][XPAD];   // X[j][k][s]

    const int tid = threadIdx.x;
    const int b   = blockIdx.z;
    const int o0  = blockIdx.y * TILE;
    const int s0  = blockIdx.x * TILE;

    const int ty = tid >> 4;   // 0..15 -> owns o pair (2*ty, 2*ty+1)
    const int tx = tid & 15;   // 0..15 -> owns s pair (2*tx, 2*tx+1)

    float accY[NN][NN][2][2];
    float accU[NN][2][2];
    #pragma unroll
    for (int i = 0; i < NN; i++) {
        #pragma unroll
        for (int oo = 0; oo < 2; oo++)
            #pragma unroll
            for (int ss = 0; ss < 2; ss++) {
                accU[i][oo][ss] = 0.f;
                #pragma unroll
                for (int j = 0; j < NN; j++) accY[i][j][oo][ss] = 0.f;
            }
    }

    // staging index helpers
    const int wo  = tid & 31;        // o within tile (weight load)
    const int wc  = tid >> 5;        // 0..7 c-group of 4 (weight load)
    const int xk  = tid >> 3;        // 0..31 k-row (x load)
    const int xs4 = (tid & 7) * 4;   // s offset (x load)

    #pragma unroll 1
    for (int k0 = 0; k0 < CC; k0 += KC) {
        // --- stage weights: A = W1+W2 and W2, transposed to [k][o] ---
        #pragma unroll
        for (int i = 0; i < NN; i++) {
            const float* gw = w + (i * CC + (o0 + wo)) * (2 * CC) + (k0 + wc * 4);
            const float4 w1 = *(const float4*)gw;
            const float4 w2 = *(const float4*)(gw + CC);
            a_s [i][wc * 4 + 0][wo] = w1.x + w2.x;
            a_s [i][wc * 4 + 1][wo] = w1.y + w2.y;
            a_s [i][wc * 4 + 2][wo] = w1.z + w2.z;
            a_s [i][wc * 4 + 3][wo] = w1.w + w2.w;
            w2_s[i][wc * 4 + 0][wo] = w2.x;
            w2_s[i][wc * 4 + 1][wo] = w2.y;
            w2_s[i][wc * 4 + 2][wo] = w2.z;
            w2_s[i][wc * 4 + 3][wo] = w2.w;
        }
        // --- stage X tiles [k][s] (natural layout, float4) ---
        #pragma unroll
        for (int j = 0; j < NN; j++) {
            const float4 vx = *(const float4*)(x + ((j * BB + b) * CC + (k0 + xk)) * SSP + s0 + xs4);
            *(float4*)&x_s[j][xk][xs4] = vx;
        }
        __syncthreads();

        #pragma unroll 2
        for (int k = 0; k < KC; k++) {
            float ao[NN][2], wv[NN][2], xv[NN][2];
            #pragma unroll
            for (int i = 0; i < NN; i++) {
                ao[i][0] = a_s [i][k][2 * ty];
                ao[i][1] = a_s [i][k][2 * ty + 1];
                wv[i][0] = w2_s[i][k][2 * ty];
                wv[i][1] = w2_s[i][k][2 * ty + 1];
                xv[i][0] = x_s [i][k][2 * tx];
                xv[i][1] = x_s [i][k][2 * tx + 1];
            }
            #pragma unroll
            for (int i = 0; i < NN; i++) {
                #pragma unroll
                for (int j = 0; j < NN; j++) {
                    accY[i][j][0][0] += ao[i][0] * xv[j][0];
                    accY[i][j][0][1] += ao[i][0] * xv[j][1];
                    accY[i][j][1][0] += ao[i][1] * xv[j][0];
                    accY[i][j][1][1] += ao[i][1] * xv[j][1];
                }
                accU[i][0][0] += wv[i][0] * xv[i][0];
                accU[i][0][1] += wv[i][0] * xv[i][1];
                accU[i][1][0] += wv[i][1] * xv[i][0];
                accU[i][1][1] += wv[i][1] * xv[i][1];
            }
        }
        __syncthreads();
    }

    // ---------------- epilogue ----------------
    const int o = o0 + 2 * ty;
    const int s = s0 + 2 * tx;

    // x at the OUTPUT channel (p includes channel): xe[j][oo][ss]
    float xe[NN][2][2];
    #pragma unroll
    for (int j = 0; j < NN; j++)
        #pragma unroll
        for (int oo = 0; oo < 2; oo++) {
            const float2 v = *(const float2*)(x + ((j * BB + b) * CC + (o + oo)) * SSP + s);
            xe[j][oo][0] = v.x;
            xe[j][oo][1] = v.y;
        }

    float bv[NN][2];
    #pragma unroll
    for (int i = 0; i < NN; i++) {
        bv[i][0] = bias[i * CC + o];
        bv[i][1] = bias[i * CC + o + 1];
    }

    #pragma unroll
    for (int i = 0; i < NN; i++) {
        #pragma unroll
        for (int oo = 0; oo < 2; oo++) {
            #pragma unroll
            for (int ss = 0; ss < 2; ss++) {
                const float uu = accU[i][oo][ss] + bv[i][oo];
                float e[NN];
                float m = 0.f;   // thresholded edges are >= 0, so 0 is a valid max seed
                #pragma unroll
                for (int j = 0; j < NN; j++) {
                    float d = fabsf(xe[j][oo][ss] - (accY[i][j][oo][ss] + uu));
                    d = (d > THRESHV) ? d : 0.f;
                    e[j] = d;
                    m = fmaxf(m, d);
                }
                float sum = 0.f, h = 0.f;
                #pragma unroll
                for (int j = 0; j < NN; j++) {
                    const float p = __expf(e[j] - m);
                    sum += p;
                    h += p * xe[j][oo][ss];
                }
                out[((i * BB + b) * CC + (o + oo)) * SSP + s + ss] = h / sum;
            }
        }
    }
}

extern "C" void kernel_launch(void* const* d_in, const int* in_sizes, int n_in,
                              void* d_out, int out_size, void* d_ws, size_t ws_size,
                              hipStream_t stream) {
    const float* x      = (const float*)d_in[0];
    const float* conv_w = (const float*)d_in[1];
    const float* conv_b = (const float*)d_in[2];
    float* out = (float*)d_out;

    dim3 grid(SSP / TILE, CC / TILE, BB);   // (32, 8, 8)
    dim3 block(256);
    fub_fused<<<grid, block, 0, stream>>>(x, conv_w, conv_b, out);
}

// Round 2
// 432.853 us; speedup vs baseline: 1.2411x; 1.2411x over previous
//
#include <hip/hip_runtime.h>
#include <math.h>

// N=5, B=8, C=256, H*W=1024
#define NN 5
#define CC 256
#define SSP 1024
#define BB 8
#define THRESHV 0.3f

typedef __attribute__((ext_vector_type(8))) short short8;   // 8 bf16 = one MFMA A/B frag
typedef __attribute__((ext_vector_type(4))) float f32x4;    // MFMA 16x16 accumulator

// ---- exact 3-way bf16 split (Dekker-style; residuals exact in fp32) ----
static __device__ __forceinline__ unsigned short f2bf(float f) {
    unsigned int u = __builtin_bit_cast(unsigned int, f);
    u = u + 0x7fffu + ((u >> 16) & 1u);          // RNE to bf16
    return (unsigned short)(u >> 16);
}
static __device__ __forceinline__ float bf2f(unsigned short h) {
    unsigned int u = ((unsigned int)h) << 16;
    return __builtin_bit_cast(float, u);
}
static __device__ __forceinline__ void split3(float a, unsigned short& h,
                                              unsigned short& m, unsigned short& l) {
    h = f2bf(a); float r1 = a - bf2f(h);
    m = f2bf(r1); float r2 = r1 - bf2f(m);
    l = f2bf(r2);
}
static __device__ __forceinline__ f32x4 MF(short8 a, short8 b, f32x4 c) {
    return __builtin_amdgcn_mfma_f32_16x16x32_bf16(a, b, c, 0, 0, 0);
}
static __device__ __forceinline__ void st4(unsigned short* p, unsigned short a,
                                           unsigned short b, unsigned short c, unsigned short d) {
    ushort4 v; v.x = a; v.y = b; v.z = c; v.w = d;
    *(ushort4*)p = v;   // 8B-aligned by construction
}

// LDS: 30 planes of [32 rows][32 bf16] with XOR-swizzled 16B units.
//   A region: planes (i*3+split), i=0..4       -> shorts [0, 15360)
//   X region: planes (j*3+split)+offset 15360  -> shorts [15360, 30720)
// unit swizzle: byte = row*64 + (quad ^ ((row>>1)&3))*16  (2-way bank alias max = free)
#define XB 15360

__global__ __launch_bounds__(512, 2)
void fub_mfma(const float* __restrict__ x,      // [5,8,256,1024]
              const float* __restrict__ w,      // [5,256,512]
              const float* __restrict__ bias,   // [5,256]
              float* __restrict__ out)          // [5,8,256,1024]
{
    __shared__ unsigned short S[30720];   // 61440 B

    const int tid  = threadIdx.x;
    const int b    = blockIdx.z;
    const int o0   = blockIdx.y * 32;
    const int s0   = blockIdx.x * 32;

    const int lane = tid & 63;
    const int wv   = tid >> 6;        // 0..7
    const int q    = wv & 3;          // tile quarter
    const int oh   = q >> 1, sh = q & 1;
    const int iset = wv >> 2;         // 0: i{0,1}  1: i{2,3,4}
    const int qd   = lane >> 4;       // MFMA k-quad

    // staging coords (256-thread halves)
    const int sub = tid >> 8;         // 0/1 -> plane parity
    const int t   = tid & 255;
    const int wo  = t >> 3;           // weights: o row 0..31
    const int wkg = t & 7;            // weights: k-group of 4
    const int xs  = t & 31;           // x: s 0..31
    const int xkq = t >> 5;           // x: k-group of 4 (0..7)

    const int wbase = wo * 32 + (((wkg >> 1) ^ ((wo >> 1) & 3)) << 3) + ((wkg & 1) << 2);
    const int xbase = xs * 32 + (((xkq >> 1) ^ ((xs >> 1) & 3)) << 3) + ((xkq & 1) << 2);

    // fragment-read coords
    const int ar    = 16 * oh + (lane & 15);              // A row (o)
    const int xr    = 16 * sh + (lane & 15);              // X row (s)
    const int asw8  = ((qd ^ ((ar >> 1) & 3)) << 3);
    const int xsw8  = ((qd ^ ((xr >> 1) & 3)) << 3);
    const int arow32 = ar * 32, xrow32 = xr * 32;

    f32x4 accY[3][5];
    f32x4 accU[3];
    #pragma unroll
    for (int ii = 0; ii < 3; ii++) {
        accU[ii] = (f32x4){0.f, 0.f, 0.f, 0.f};
        #pragma unroll
        for (int j = 0; j < NN; j++) accY[ii][j] = (f32x4){0.f, 0.f, 0.f, 0.f};
    }

    float w2sav[3][4];   // W2 fp32 values held for the mid-chunk restage

    #pragma unroll 1
    for (int k0 = 0; k0 < CC; k0 += 32) {
        if (k0) __syncthreads();

        // ---- stage A = W1+W2 (split x3) into A region; keep W2 in regs ----
        #pragma unroll
        for (int rep = 0; rep < 3; rep++) {
            const int i = rep * 2 + sub;
            if (i < NN) {
                const float* gw = w + (size_t)(i * CC + o0 + wo) * (2 * CC) + k0 + wkg * 4;
                const float4 w1 = *(const float4*)gw;
                const float4 w2 = *(const float4*)(gw + CC);
                w2sav[rep][0] = w2.x; w2sav[rep][1] = w2.y;
                w2sav[rep][2] = w2.z; w2sav[rep][3] = w2.w;
                float av[4] = {w1.x + w2.x, w1.y + w2.y, w1.z + w2.z, w1.w + w2.w};
                unsigned short h[4], m[4], l[4];
                #pragma unroll
                for (int r = 0; r < 4; r++) split3(av[r], h[r], m[r], l[r]);
                unsigned short* p = &S[i * 3 * 1024 + wbase];
                st4(p,        h[0], h[1], h[2], h[3]);
                st4(p + 1024, m[0], m[1], m[2], m[3]);
                st4(p + 2048, l[0], l[1], l[2], l[3]);
            }
        }
        // ---- stage X (split x3) into X region ----
        #pragma unroll
        for (int rep = 0; rep < 3; rep++) {
            const int j = rep * 2 + sub;
            if (j < NN) {
                const float* gx = x + (size_t)((j * BB + b) * CC + k0 + xkq * 4) * SSP + s0 + xs;
                float v[4] = {gx[0], gx[SSP], gx[2 * SSP], gx[3 * SSP]};
                unsigned short h[4], m[4], l[4];
                #pragma unroll
                for (int r = 0; r < 4; r++) split3(v[r], h[r], m[r], l[r]);
                unsigned short* p = &S[XB + j * 3 * 1024 + xbase];
                st4(p,        h[0], h[1], h[2], h[3]);
                st4(p + 1024, m[0], m[1], m[2], m[3]);
                st4(p + 2048, l[0], l[1], l[2], l[3]);
            }
        }
        __syncthreads();

        // ---- X fragments for all (j, split): resident in registers ----
        short8 xf[NN][3];
        #pragma unroll
        for (int j = 0; j < NN; j++)
            #pragma unroll
            for (int sp = 0; sp < 3; sp++)
                xf[j][sp] = *(const short8*)&S[XB + (j * 3 + sp) * 1024 + xrow32 + xsw8];

        // ---- Y MFMAs: 6 split-products per (i,j) plane ----
#define YPLANES(IB, NI_)                                                        \
        {                                                                       \
            _Pragma("unroll")                                                   \
            for (int ii = 0; ii < NI_; ii++) {                                  \
                const int i = IB + ii;                                          \
                const unsigned short* ap = &S[i * 3 * 1024 + arow32 + asw8];    \
                const short8 ah = *(const short8*)(ap);                         \
                const short8 am = *(const short8*)(ap + 1024);                  \
                const short8 al = *(const short8*)(ap + 2048);                  \
                _Pragma("unroll")                                               \
                for (int j = 0; j < NN; j++) {                                  \
                    f32x4 c = accY[ii][j];                                      \
                    c = MF(ah, xf[j][0], c);                                    \
                    c = MF(ah, xf[j][1], c);                                    \
                    c = MF(am, xf[j][0], c);                                    \
                    c = MF(am, xf[j][1], c);                                    \
                    c = MF(ah, xf[j][2], c);                                    \
                    c = MF(al, xf[j][0], c);                                    \
                    accY[ii][j] = c;                                            \
                }                                                               \
            }                                                                   \
        }
        if (iset == 0) { YPLANES(0, 2) } else { YPLANES(2, 3) }
        __syncthreads();

        // ---- restage W2 (from regs) into the A region ----
        #pragma unroll
        for (int rep = 0; rep < 3; rep++) {
            const int i = rep * 2 + sub;
            if (i < NN) {
                unsigned short h[4], m[4], l[4];
                #pragma unroll
                for (int r = 0; r < 4; r++) split3(w2sav[rep][r], h[r], m[r], l[r]);
                unsigned short* p = &S[i * 3 * 1024 + wbase];
                st4(p,        h[0], h[1], h[2], h[3]);
                st4(p + 1024, m[0], m[1], m[2], m[3]);
                st4(p + 2048, l[0], l[1], l[2], l[3]);
            }
        }
        __syncthreads();

        // ---- U MFMAs: U[i] = W2_i @ X_i ----
#define UPLANES(IB, NI_)                                                        \
        {                                                                       \
            _Pragma("unroll")                                                   \
            for (int ii = 0; ii < NI_; ii++) {                                  \
                const int i = IB + ii;                                          \
                const unsigned short* wp = &S[i * 3 * 1024 + arow32 + asw8];    \
                const short8 wh = *(const short8*)(wp);                         \
                const short8 wm = *(const short8*)(wp + 1024);                  \
                const short8 wl = *(const short8*)(wp + 2048);                  \
                f32x4 u = accU[ii];                                             \
                u = MF(wh, xf[i][0], u);                                        \
                u = MF(wh, xf[i][1], u);                                        \
                u = MF(wm, xf[i][0], u);                                        \
                u = MF(wm, xf[i][1], u);                                        \
                u = MF(wh, xf[i][2], u);                                        \
                u = MF(wl, xf[i][0], u);                                        \
                accU[ii] = u;                                                   \
            }                                                                   \
        }
        if (iset == 0) { UPLANES(0, 2) } else { UPLANES(2, 3) }
    }

    // ---------------- epilogue ----------------
    // C/D layout: col(s) = lane&15, row(o) = qd*4 + reg  [m89/m91-verified]
    const int sg   = s0 + 16 * sh + (lane & 15);
    const int og0  = o0 + 16 * oh + 4 * qd;

    float xe[NN][4];
    #pragma unroll
    for (int j = 0; j < NN; j++) {
        const float* px = x + (size_t)((j * BB + b) * CC + og0) * SSP + sg;
        #pragma unroll
        for (int r = 0; r < 4; r++) xe[j][r] = px[r * SSP];
    }

#define EPILOGUE(IB, NI_)                                                       \
    {                                                                           \
        _Pragma("unroll")                                                       \
        for (int ii = 0; ii < NI_; ii++) {                                      \
            const int i = IB + ii;                                              \
            _Pragma("unroll")                                                   \
            for (int r = 0; r < 4; r++) {                                       \
                const float uu = accU[ii][r] + bias[i * CC + og0 + r];          \
                float e[NN]; float mx = 0.f;                                    \
                _Pragma("unroll")                                               \
                for (int j = 0; j < NN; j++) {                                  \
                    float d = fabsf(xe[j][r] - (accY[ii][j][r] + uu));          \
                    d = (d > THRESHV) ? d : 0.f;                                \
                    e[j] = d; mx = fmaxf(mx, d);                                \
                }                                                               \
                float sum = 0.f, hv = 0.f;                                      \
                _Pragma("unroll")                                               \
                for (int j = 0; j < NN; j++) {                                  \
                    const float p = __expf(e[j] - mx);                          \
                    sum += p; hv += p * xe[j][r];                               \
                }                                                               \
                out[(size_t)((i * BB + b) * CC + og0 + r) * SSP + sg] = hv / sum; \
            }                                                                   \
        }                                                                       \
    }
    if (iset == 0) { EPILOGUE(0, 2) } else { EPILOGUE(2, 3) }
}

extern "C" void kernel_launch(void* const* d_in, const int* in_sizes, int n_in,
                              void* d_out, int out_size, void* d_ws, size_t ws_size,
                              hipStream_t stream) {
    const float* x      = (const float*)d_in[0];
    const float* conv_w = (const float*)d_in[1];
    const float* conv_b = (const float*)d_in[2];
    float* out = (float*)d_out;

    dim3 grid(SSP / 32, CC / 32, BB);   // (32, 8, 8) = 2048 blocks
    dim3 block(512);
    fub_mfma<<<grid, block, 0, stream>>>(x, conv_w, conv_b, out);
}